// Round 12
// baseline (1290.253 us; speedup 1.0000x reference)
//
#include <hip/hip_runtime.h>

typedef _Float16 half_t;
typedef __attribute__((ext_vector_type(8))) _Float16 h8_t;
typedef __attribute__((ext_vector_type(4))) _Float16 h4_t;
typedef __attribute__((ext_vector_type(4))) float f4_t;

#define NN      50000
#define NE      800000
#define NG      256
#define NODE_IN 92
#define EDGE_IN 41

__device__ __forceinline__ float softplus_f(float x) {
  return fmaxf(x, 0.0f) + __logf(1.0f + __expf(-fabsf(x)));
}
__device__ __forceinline__ unsigned pk2(float a, float b) {
  return __builtin_bit_cast(unsigned, __builtin_amdgcn_cvt_pkrtz(a, b));
}

// ---------- weight prep: fp32 [K][N] -> f16 [N][K] (per conv layer) ----------
__global__ __launch_bounds__(256) void prep_weights_kernel(
    const float* __restrict__ e1W, const float* __restrict__ e2W,
    const float* __restrict__ nW,
    half_t* __restrict__ W1T, half_t* __restrict__ W2T, half_t* __restrict__ WnT)
{
  int idx = blockIdx.x * 256 + threadIdx.x;        // 0 .. 491519 (exact grid 1920)
  if (idx < 294912) {                              // W1T: 3 x 256 x 384
    int i = idx / 98304, rem = idx % 98304;
    int n = rem / 384, k = rem % 384;
    W1T[idx] = (half_t)e1W[i * 98304 + k * 256 + n];
  } else if (idx < 393216) {                       // W2T: 3 x 128 x 256
    int o = idx - 294912;
    int i = o / 32768, rem = o % 32768;
    int n = rem / 256, k = rem % 256;
    W2T[o] = (half_t)e2W[i * 32768 + k * 128 + n];
  } else {                                         // WnT: 3 x 128 x 256
    int o = idx - 393216;
    int i = o / 32768, rem = o % 32768;
    int n = rem / 256, k = rem % 256;
    WnT[o] = (half_t)nW[i * 32768 + k * 128 + n];
  }
}

// ---------- composite ea weights: Wc[L] = We @ W1c[L] (f16 [256][64]),
//            b1c[L] = e1b[L] + be @ W1c[L] (fp32) ----------
__global__ __launch_bounds__(256) void prep_comp_kernel(
    const float* __restrict__ e1W, const float* __restrict__ e1b,
    const float* __restrict__ eW, const float* __restrict__ eb,
    half_t* __restrict__ WcT, float* __restrict__ b1c)
{
  int idx = blockIdx.x * 256 + threadIdx.x;   // grid 195 -> 49920
  if (idx < 49152) {                          // (L, n, k): 3 x 256 x 64
    int L = idx / 16384, rem = idx % 16384;
    int n = rem / 64, k = rem % 64;
    float s = 0.f;
    if (k < EDGE_IN) {
      const float* w1 = e1W + (size_t)L * 98304 + 256 * 256 + n;  // rows 256+j
      const float* we = eW + k * 128;
      for (int j = 0; j < 128; ++j) s += we[j] * w1[(size_t)j * 256];
    }
    WcT[idx] = (half_t)s;                     // layout [L][n][k64]
  } else if (idx < 49920) {
    int o = idx - 49152;                      // (L, n): 3 x 256
    int L = o / 256, n = o % 256;
    float s = e1b[L * 256 + n];
    const float* w1 = e1W + (size_t)L * 98304 + 256 * 256 + n;
    for (int j = 0; j < 128; ++j) s += eb[j] * w1[(size_t)j * 256];
    b1c[o] = s;
  }
}

// ---------- node embedding: h = x @ node_W + node_b (fp32 + f16 copy) ----------
__global__ __launch_bounds__(256) void node_embed_kernel(
    const float* __restrict__ x, const float* __restrict__ W,
    const float* __restrict__ bias, float* __restrict__ hf,
    half_t* __restrict__ h16)
{
  __shared__ float xs[16 * NODE_IN];
  int n0 = blockIdx.x * 16;
  for (int i = threadIdx.x; i < 16 * NODE_IN; i += 256)
    xs[i] = x[(size_t)n0 * NODE_IN + i];
  __syncthreads();
  int ch = threadIdx.x & 127, g = threadIdx.x >> 7;
  float acc[8] = {0.f,0.f,0.f,0.f,0.f,0.f,0.f,0.f};
  for (int k = 0; k < NODE_IN; ++k) {
    float w = W[k * 128 + ch];
    #pragma unroll
    for (int u = 0; u < 8; ++u) acc[u] += xs[(g + 2*u) * NODE_IN + k] * w;
  }
  float bv = bias[ch];
  #pragma unroll
  for (int u = 0; u < 8; ++u) {
    int n = n0 + g + 2*u;
    float v = acc[u] + bv;
    hf[(size_t)n*128 + ch] = v;
    h16[(size_t)n*128 + ch] = (half_t)v;
  }
}

// ---------- ea convert: edge_attr fp32 -> f16 [NE][64] (K padded), CSR-permuted ----------
__global__ __launch_bounds__(256) void ea_convert_kernel(
    const float* __restrict__ ea, const int* __restrict__ ipos,
    half_t* __restrict__ eaF)
{
  __shared__ float es[64 * EDGE_IN];
  __shared__ int sip[64];
  int e0 = blockIdx.x * 64;
  for (int i = threadIdx.x; i < 64 * EDGE_IN; i += 256)
    es[i] = ea[(size_t)e0 * EDGE_IN + i];
  if (threadIdx.x < 64) sip[threadIdx.x] = ipos[e0 + threadIdx.x];
  __syncthreads();
  #pragma unroll
  for (int it = 0; it < 2; ++it) {
    int idx = threadIdx.x + it * 256;   // 0..511 = 64 edges x 8 chunks(8 cols)
    int e = idx >> 3, c = idx & 7;
    int c0 = c * 8;
    float f[8];
    #pragma unroll
    for (int j = 0; j < 8; ++j) {
      int col = c0 + j;
      f[j] = (col < EDGE_IN) ? es[e * EDGE_IN + col] : 0.f;
    }
    uint4 pk;
    pk.x = pk2(f[0], f[1]); pk.y = pk2(f[2], f[3]);
    pk.z = pk2(f[4], f[5]); pk.w = pk2(f[6], f[7]);
    *reinterpret_cast<uint4*>(eaF + (size_t)sip[e] * 64 + c0) = pk;
  }
}

// ---------- CSR build (by destination node = edge_index[1]) ----------
__global__ __launch_bounds__(256) void csr_count_kernel(
    const int* __restrict__ col, int* __restrict__ cnt)
{
  int e = blockIdx.x * 256 + threadIdx.x;
  atomicAdd(&cnt[col[e]], 1);
}

// parallel 3-kernel exclusive scan of cnt -> cur
__global__ __launch_bounds__(256) void scan_block_kernel(
    const int* __restrict__ cnt, int* __restrict__ cur, int* __restrict__ bsum)
{
  __shared__ int buf[256];
  int t = threadIdx.x;
  int i = blockIdx.x * 256 + t;
  int v = (i < NN) ? cnt[i] : 0;
  buf[t] = v;
  __syncthreads();
  for (int off = 1; off < 256; off <<= 1) {
    int y = (t >= off) ? buf[t - off] : 0;
    __syncthreads();
    buf[t] += y;
    __syncthreads();
  }
  if (i < NN) cur[i] = buf[t] - v;
  if (t == 255) bsum[blockIdx.x] = buf[255];
}

__global__ __launch_bounds__(256) void scan_top_kernel(
    const int* __restrict__ bsum, int* __restrict__ bbase, int nblk)
{
  __shared__ int buf[256];
  int t = threadIdx.x;
  int v = (t < nblk) ? bsum[t] : 0;
  buf[t] = v;
  __syncthreads();
  for (int off = 1; off < 256; off <<= 1) {
    int y = (t >= off) ? buf[t - off] : 0;
    __syncthreads();
    buf[t] += y;
    __syncthreads();
  }
  if (t < nblk) bbase[t] = buf[t] - v;
}

__global__ __launch_bounds__(256) void scan_add_kernel(
    int* __restrict__ cur, const int* __restrict__ bbase)
{
  int i = blockIdx.x * 256 + threadIdx.x;
  if (i < NN) cur[i] += bbase[blockIdx.x];
}

__global__ __launch_bounds__(256) void csr_fill_kernel(
    const int* __restrict__ row, const int* __restrict__ col,
    int* __restrict__ cur,
    int* __restrict__ rowv, int* __restrict__ colv, int* __restrict__ ipos)
{
  int e = blockIdx.x * 256 + threadIdx.x;
  int c = col[e];
  int pos = atomicAdd(&cur[c], 1);
  rowv[pos] = row[e];
  colv[pos] = c;
  ipos[e] = pos;
}

// ---------- per-layer node precompute: u = h@W1a + b1c, v = h@W1b (f16) ----------
__global__ __launch_bounds__(256) void uv_kernel(
    const half_t* __restrict__ h16, const half_t* __restrict__ W1T,
    const float* __restrict__ b1c,
    half_t* __restrict__ u16, half_t* __restrict__ v16)
{
  __shared__ char smem[64 * 256];   // 16KB: h tile [64node][128] f16, swizzled
  const int tid = threadIdx.x;
  const int n0 = blockIdx.x * 64;

  #pragma unroll
  for (int it = 0; it < 4; ++it) {
    int idx = tid + it * 256;        // 0..1023 = 64 nodes x 16 chunks(16B)
    int r = idx >> 4, c = idx & 15;
    int node = n0 + r;
    uint4 w = make_uint4(0u, 0u, 0u, 0u);
    if (node < NN) w = *reinterpret_cast<const uint4*>(h16 + (size_t)node * 128 + c * 8);
    unsigned o = (unsigned)(r * 256 + c * 16) ^ (unsigned)((r & 7) << 4);
    *reinterpret_cast<uint4*>(smem + o) = w;
  }
  __syncthreads();

  const int lane = tid & 63, wave = tid >> 6;
  const int lr = lane & 15, lg = lane >> 4;

  #pragma unroll
  for (int pass = 0; pass < 2; ++pass) {
    const half_t* Ww = W1T + (size_t)(wave * 64) * 384 + pass * 128;
    f4_t acc[4][4] = {};
    for (int ks = 0; ks < 4; ++ks) {
      h8_t a[4], b[4];
      #pragma unroll
      for (int m = 0; m < 4; ++m)
        a[m] = *reinterpret_cast<const h8_t*>(Ww + (size_t)(m * 16 + lr) * 384 + ks * 32 + lg * 8);
      #pragma unroll
      for (int n = 0; n < 4; ++n) {
        int r = n * 16 + lr;
        unsigned o = (unsigned)(r * 256 + ks * 64 + lg * 16) ^ (unsigned)((r & 7) << 4);
        b[n] = *reinterpret_cast<const h8_t*>(smem + o);
      }
      #pragma unroll
      for (int m = 0; m < 4; ++m)
        #pragma unroll
        for (int n = 0; n < 4; ++n)
          acc[m][n] = __builtin_amdgcn_mfma_f32_16x16x32_f16(a[m], b[n], acc[m][n], 0, 0, 0);
    }
    half_t* dst = pass ? v16 : u16;
    #pragma unroll
    for (int m = 0; m < 4; ++m) {
      int chb = wave * 64 + m * 16 + lg * 4;
      float bb0 = 0.f, bb1 = 0.f, bb2 = 0.f, bb3 = 0.f;
      if (pass == 0) { bb0 = b1c[chb]; bb1 = b1c[chb+1]; bb2 = b1c[chb+2]; bb3 = b1c[chb+3]; }
      #pragma unroll
      for (int n = 0; n < 4; ++n) {
        int node = n0 + n * 16 + lr;
        if (node < NN) {
          uint2 pk;
          pk.x = pk2(acc[m][n][0] + bb0, acc[m][n][1] + bb1);
          pk.y = pk2(acc[m][n][2] + bb2, acc[m][n][3] + bb3);
          *reinterpret_cast<uint2*>(dst + (size_t)node * 256 + chb) = pk;
        }
      }
    }
  }
}

// ---------- fused edge MLP + segmented scatter-reduce (CSR order, 40KB LDS):
//   edge-half passes keep accumulator liveness low -> no spills at 8 waves/EU.
__global__ __launch_bounds__(512, 8) void conv_edge_kernel(
    const half_t* __restrict__ u16, const half_t* __restrict__ v16,
    const half_t* __restrict__ eaF,
    const int* __restrict__ rowv, const int* __restrict__ colv,
    const half_t* __restrict__ WcT,
    const half_t* __restrict__ W2T, const float* __restrict__ b2,
    float* __restrict__ aggrF)
{
  __shared__ char smem[64 * 512 + 64 * 128];  // 32KB s/P/out + 8KB ea = 40960
  const int tid = threadIdx.x;

  // bijective XCD-chunked remap
  const int nwg = gridDim.x;
  const int q = nwg >> 3, r = nwg & 7;
  const int xcd = blockIdx.x & 7, slot = blockIdx.x >> 3;
  const int swz = (xcd < r ? xcd * (q + 1) : r * (q + 1) + (xcd - r) * q) + slot;
  const int e0 = swz * 64;                    // CSR position base

  // stage s = u16[rowv] + v16[colv] -> LDS
  #pragma unroll
  for (int it = 0; it < 4; ++it) {
    int idx = tid + it * 512;        // 0..2047 = 64 edges x 32 chunks(16B)
    int e = idx >> 5, c = idx & 31;
    int nr = rowv[e0 + e], nc = colv[e0 + e];
    h8_t su = *reinterpret_cast<const h8_t*>(u16 + (size_t)nr * 256 + c * 8);
    h8_t sv = *reinterpret_cast<const h8_t*>(v16 + (size_t)nc * 256 + c * 8);
    h8_t s = su + sv;
    unsigned o = (unsigned)(e * 512 + c * 16) ^ (unsigned)((e & 7) << 4);
    *reinterpret_cast<h8_t*>(smem + o) = s;
  }
  // stage ea tile (contiguous, K=64 f16 = 128B/edge)
  {
    int e = tid >> 3, c = tid & 7;   // 512 items = 64 edges x 8 chunks(16B)
    uint4 w = *reinterpret_cast<const uint4*>(eaF + (size_t)(e0 + e) * 64 + c * 8);
    unsigned o = (unsigned)(32768 + e * 128 + c * 16) ^ (unsigned)((e & 7) << 4);
    *reinterpret_cast<uint4*>(smem + o) = w;
  }
  __syncthreads();

  const int lane = tid & 63, wave = tid >> 6;   // wave 0..7
  const int lr = lane & 15, lg = lane >> 4;

  // GEMM1 + ep1 in two edge-half passes: acc[2][2] live (16 regs)
  const half_t* W1w = WcT + (size_t)(wave * 32) * 64;
  #pragma unroll
  for (int pass = 0; pass < 2; ++pass) {
    f4_t acc[2][2] = {};
    #pragma unroll
    for (int ks = 0; ks < 2; ++ks) {
      h8_t a[2], b[2];
      #pragma unroll
      for (int m = 0; m < 2; ++m)
        a[m] = *reinterpret_cast<const h8_t*>(W1w + (size_t)(m * 16 + lr) * 64 + ks * 32 + lg * 8);
      #pragma unroll
      for (int n = 0; n < 2; ++n) {
        int e = pass * 32 + n * 16 + lr;
        unsigned o = (unsigned)(32768 + e * 128 + ks * 64 + lg * 16) ^ (unsigned)((e & 7) << 4);
        b[n] = *reinterpret_cast<const h8_t*>(smem + o);
      }
      #pragma unroll
      for (int m = 0; m < 2; ++m)
        #pragma unroll
        for (int n = 0; n < 2; ++n)
          acc[m][n] = __builtin_amdgcn_mfma_f32_16x16x32_f16(a[m], b[n], acc[m][n], 0, 0, 0);
    }
    // ep1 (this half, thread-local in-place): P = sp(acc + s)
    #pragma unroll
    for (int m = 0; m < 2; ++m) {
      int chb = wave * 32 + m * 16 + lg * 4;
      #pragma unroll
      for (int n = 0; n < 2; ++n) {
        int e = pass * 32 + n * 16 + lr;
        unsigned o = (unsigned)(e * 512 + chb * 2) ^ (unsigned)((e & 7) << 4);
        h4_t s = *reinterpret_cast<const h4_t*>(smem + o);
        float v0 = softplus_f(acc[m][n][0] + (float)s[0]);
        float v1 = softplus_f(acc[m][n][1] + (float)s[1]);
        float v2 = softplus_f(acc[m][n][2] + (float)s[2]);
        float v3 = softplus_f(acc[m][n][3] + (float)s[3]);
        uint2 pk;
        pk.x = pk2(v0, v1);
        pk.y = pk2(v2, v3);
        *reinterpret_cast<uint2*>(smem + o) = pk;
      }
    }
  }
  __syncthreads();   // P complete

  // GEMM2 + ep2 in two edge-half passes: acc2[2] live (8 regs).
  // ep2 of pass p overwrites P rows [p*32,p*32+32) which pass (1-p) never reads.
  const half_t* W2w = W2T + (size_t)(wave * 16) * 256;
  const int chb2 = wave * 16 + lg * 4;
  const float bb0 = b2[chb2 + 0], bb1 = b2[chb2 + 1],
              bb2v = b2[chb2 + 2], bb3 = b2[chb2 + 3];
  #pragma unroll
  for (int pass = 0; pass < 2; ++pass) {
    f4_t acc2[2] = {};
    for (int ks = 0; ks < 8; ++ks) {
      h8_t a2 = *reinterpret_cast<const h8_t*>(W2w + (size_t)lr * 256 + ks * 32 + lg * 8);
      h8_t b2r[2];
      #pragma unroll
      for (int n = 0; n < 2; ++n) {
        int e = pass * 32 + n * 16 + lr;
        unsigned o = (unsigned)(e * 512 + ks * 64 + lg * 16) ^ (unsigned)((e & 7) << 4);
        b2r[n] = *reinterpret_cast<const h8_t*>(smem + o);
      }
      #pragma unroll
      for (int n = 0; n < 2; ++n)
        acc2[n] = __builtin_amdgcn_mfma_f32_16x16x32_f16(a2, b2r[n], acc2[n], 0, 0, 0);
    }
    __syncthreads();   // all waves done reading this half's P rows

    if (pass == 0 && tid < 64)   // scol -> ea region (free after GEMM1)
      *reinterpret_cast<int*>(smem + 32768 + tid * 4) = colv[e0 + tid];

    #pragma unroll
    for (int n = 0; n < 2; ++n) {
      int e = pass * 32 + n * 16 + lr;
      float4 v;
      v.x = softplus_f(acc2[n][0] + bb0);
      v.y = softplus_f(acc2[n][1] + bb1);
      v.z = softplus_f(acc2[n][2] + bb2v);
      v.w = softplus_f(acc2[n][3] + bb3);
      unsigned o = (unsigned)(e * 512 + chb2 * 4) ^ (unsigned)((e & 7) << 4);
      *reinterpret_cast<float4*>(smem + o) = v;
    }
  }
  __syncthreads();   // all f32 out rows + scol visible

  // segmented reduce over sorted cols -> atomicAdd into aggrF
  {
    const int* scol = reinterpret_cast<const int*>(smem + 32768);
    int ch = tid & 127, g2 = tid >> 7;   // 4 groups x 16 edges
    int ebase = g2 * 16;
    float a = 0.f;
    int curc = scol[ebase];
    #pragma unroll
    for (int k = 0; k < 16; ++k) {
      int e = ebase + k;
      int c = scol[e];
      if (c != curc) {
        atomicAdd(&aggrF[(size_t)curc * 128 + ch], a);
        a = 0.f; curc = c;
      }
      unsigned o = (unsigned)(e * 512 + ch * 4) ^ (unsigned)((e & 7) << 4);
      a += *reinterpret_cast<const float*>(smem + o);
    }
    atomicAdd(&aggrF[(size_t)curc * 128 + ch], a);
  }
}

// ---------- node update: h = sp([h | aggrF] @ Wn + bn) + h  (8-wave) ----------
__global__ __launch_bounds__(512, 4) void conv_node_kernel(
    half_t* __restrict__ h16, const float* __restrict__ aggrF,
    const half_t* __restrict__ WnT, const float* __restrict__ bn,
    float* __restrict__ hf)
{
  __shared__ char smem[64 * 256 * 2];   // 32 KB A = [h | aggr] f16, swizzled
  const int tid = threadIdx.x;
  const int n0 = blockIdx.x * 64;

  #pragma unroll
  for (int it = 0; it < 4; ++it) {
    int idx = tid + it * 512;          // 0..2047 = 64 rows x 32 chunks
    int r = idx >> 5, c = idx & 31;
    int node = n0 + r;
    uint4 v = make_uint4(0u, 0u, 0u, 0u);
    if (node < NN) {
      if (c < 16) {
        v = *reinterpret_cast<const uint4*>(h16 + (size_t)node * 128 + c * 8);
      } else {
        const float* src = aggrF + (size_t)node * 128 + (c - 16) * 8;
        float4 f0 = *reinterpret_cast<const float4*>(src);
        float4 f1 = *reinterpret_cast<const float4*>(src + 4);
        v.x = pk2(f0.x, f0.y); v.y = pk2(f0.z, f0.w);
        v.z = pk2(f1.x, f1.y); v.w = pk2(f1.z, f1.w);
      }
    }
    unsigned o = (unsigned)(r * 512 + c * 16) ^ (unsigned)((r & 7) << 4);
    *reinterpret_cast<uint4*>(smem + o) = v;
  }
  __syncthreads();

  const int lane = tid & 63, wave = tid >> 6;
  const int lr = lane & 15, lg = lane >> 4;
  const int c0 = wave * 16;
  f4_t acc[4] = {};
  for (int ks = 0; ks < 8; ++ks) {
    h8_t a[4], b;
    #pragma unroll
    for (int m = 0; m < 4; ++m) {
      int row = m * 16 + lr;
      unsigned o = (unsigned)(row * 512 + ks * 64 + lg * 16) ^ (unsigned)((row & 7) << 4);
      a[m] = *reinterpret_cast<const h8_t*>(smem + o);
    }
    b = *reinterpret_cast<const h8_t*>(WnT + (size_t)(c0 + lr) * 256 + ks * 32 + lg * 8);
    #pragma unroll
    for (int m = 0; m < 4; ++m)
      acc[m] = __builtin_amdgcn_mfma_f32_16x16x32_f16(a[m], b, acc[m], 0, 0, 0);
  }
  #pragma unroll
  for (int m = 0; m < 4; ++m)
    #pragma unroll
    for (int r = 0; r < 4; ++r) {
      int row = m * 16 + lg * 4 + r;
      int col = c0 + lr;
      int node = n0 + row;
      if (node < NN) {
        float v = softplus_f(acc[m][r] + bn[col]) + hf[(size_t)node * 128 + col];
        hf[(size_t)node * 128 + col] = v;
        h16[(size_t)node * 128 + col] = (half_t)v;
      }
    }
}

// ---------- mean pool (run-length compressed atomics; batch is sorted) ----------
__global__ __launch_bounds__(128) void pool_kernel(
    const float* __restrict__ hf, const int* __restrict__ batch,
    float* __restrict__ gsum, int* __restrict__ gcnt)
{
  int t = threadIdx.x;
  int n0 = blockIdx.x * 16;
  float acc = 0.f;
  int curb = batch[n0];
  for (int i = 0; i < 16; ++i) {
    int n = n0 + i;
    int b = batch[n];
    if (b != curb) { atomicAdd(&gsum[curb * 128 + t], acc); acc = 0.f; curb = b; }
    acc += hf[(size_t)n * 128 + t];
  }
  atomicAdd(&gsum[curb * 128 + t], acc);
  if (t == 0) {
    int c = 0, cb = batch[n0];
    for (int i = 0; i < 16; ++i) {
      int b = batch[n0 + i];
      if (b != cb) { atomicAdd(&gcnt[cb], c); c = 0; cb = b; }
      ++c;
    }
    atomicAdd(&gcnt[cb], c);
  }
}

// ---------- shared MLP + task heads (one block per graph) ----------
__global__ __launch_bounds__(128) void heads_kernel(
    const float* __restrict__ gsum, const int* __restrict__ gcnt,
    const float* __restrict__ sW1, const float* __restrict__ sb1,
    const float* __restrict__ sW2, const float* __restrict__ sb2,
    const float* __restrict__ hW, const float* __restrict__ hb,
    const float* __restrict__ hoW, const float* __restrict__ hob,
    float* __restrict__ out)
{
  int b = blockIdx.x, t = threadIdx.x;
  __shared__ float va[128], vb[128], vc[128], red[128];
  float inv = 1.0f / fmaxf((float)gcnt[b], 1.0f);
  va[t] = gsum[b * 128 + t] * inv;
  __syncthreads();
  { float a = 0.f;
    for (int k = 0; k < 128; ++k) a += va[k] * sW1[k * 128 + t];
    float r = softplus_f(a + sb1[t]);
    __syncthreads(); vb[t] = r; __syncthreads(); }
  { float a = 0.f;
    for (int k = 0; k < 128; ++k) a += vb[k] * sW2[k * 128 + t];
    float r = softplus_f(a + sb2[t]);
    __syncthreads(); va[t] = r; __syncthreads(); }   // va = g2 (kept live)
  for (int p = 0; p < 3; ++p) {
    { float a = 0.f;
      for (int k = 0; k < 128; ++k) a += va[k] * hW[((p * 2 + 0) * 128 + k) * 128 + t];
      float r = softplus_f(a + hb[(p * 2 + 0) * 128 + t]);
      __syncthreads(); vb[t] = r; __syncthreads(); }
    { float a = 0.f;
      for (int k = 0; k < 128; ++k) a += vb[k] * hW[((p * 2 + 1) * 128 + k) * 128 + t];
      float r = softplus_f(a + hb[(p * 2 + 1) * 128 + t]);
      __syncthreads(); vc[t] = r; __syncthreads(); }
    red[t] = vc[t] * hoW[p * 128 + t];
    __syncthreads();
    for (int s = 64; s > 0; s >>= 1) {
      if (t < s) red[t] += red[t + s];
      __syncthreads();
    }
    if (t == 0) out[p * NG + b] = red[0] + hob[p];
    __syncthreads();
  }
}

extern "C" void kernel_launch(void* const* d_in, const int* in_sizes, int n_in,
                              void* d_out, int out_size, void* d_ws, size_t ws_size,
                              hipStream_t stream)
{
  const float* x     = (const float*)d_in[0];
  const float* eattr = (const float*)d_in[1];
  const float* nodeW = (const float*)d_in[2];
  const float* nodeb = (const float*)d_in[3];
  const float* edgeW = (const float*)d_in[4];
  const float* edgeb = (const float*)d_in[5];
  const float* e1W   = (const float*)d_in[6];
  const float* e1b   = (const float*)d_in[7];
  const float* e2W   = (const float*)d_in[8];
  const float* e2b   = (const float*)d_in[9];
  const float* nW    = (const float*)d_in[10];
  const float* nb    = (const float*)d_in[11];
  const float* sW1   = (const float*)d_in[12];
  const float* sb1   = (const float*)d_in[13];
  const float* sW2   = (const float*)d_in[14];
  const float* sb2   = (const float*)d_in[15];
  const float* hW    = (const float*)d_in[16];
  const float* hb    = (const float*)d_in[17];
  const float* hoW   = (const float*)d_in[18];
  const float* hob   = (const float*)d_in[19];
  const int*   eidx  = (const int*)d_in[20];
  const int*   batch = (const int*)d_in[21];
  float* out = (float*)d_out;

  char* base = (char*)d_ws;
  size_t woff = 0;
  auto alloc = [&](size_t bytes) -> char* {
    char* r = base + woff;
    woff = (woff + bytes + 255) & ~(size_t)255;
    return r;
  };
  float*  hf     = (float*) alloc((size_t)NN * 128 * 4);
  half_t* h16    = (half_t*)alloc((size_t)NN * 128 * 2);
  half_t* eaF    = (half_t*)alloc((size_t)NE * 64 * 2);
  float*  aggrF  = (float*) alloc((size_t)NN * 128 * 4);
  half_t* u16    = (half_t*)alloc((size_t)NN * 256 * 2);
  half_t* v16    = (half_t*)alloc((size_t)NN * 256 * 2);
  half_t* W1T    = (half_t*)alloc((size_t)3 * 256 * 384 * 2);
  half_t* W2T    = (half_t*)alloc((size_t)3 * 128 * 256 * 2);
  half_t* WnT    = (half_t*)alloc((size_t)3 * 128 * 256 * 2);
  half_t* WcT    = (half_t*)alloc((size_t)3 * 256 * 64 * 2);
  float*  b1c    = (float*) alloc((size_t)3 * 256 * 4);
  int* cnt    = (int*)alloc((size_t)NN * 4);
  int* cur    = (int*)alloc((size_t)NN * 4);
  int* bsum   = (int*)alloc(256 * 4);
  int* bbase  = (int*)alloc(256 * 4);
  int* rowv   = (int*)alloc((size_t)NE * 4);
  int* colv   = (int*)alloc((size_t)NE * 4);
  int* ipos   = (int*)alloc((size_t)NE * 4);
  float* gsum = (float*)alloc((size_t)NG * 128 * 4);
  int*   gcnt = (int*)alloc((size_t)NG * 4);
  if (woff > ws_size) return;   // workspace too small: launch nothing (fail loud)

  const int NSCAN = (NN + 255) / 256;   // 196

  hipMemsetAsync(cnt, 0, (size_t)NN * 4, stream);
  hipMemsetAsync(gsum, 0, (size_t)NG * 128 * 4, stream);
  hipMemsetAsync(gcnt, 0, (size_t)NG * 4, stream);

  csr_count_kernel<<<NE / 256, 256, 0, stream>>>(eidx + NE, cnt);
  scan_block_kernel<<<NSCAN, 256, 0, stream>>>(cnt, cur, bsum);
  scan_top_kernel<<<1, 256, 0, stream>>>(bsum, bbase, NSCAN);
  scan_add_kernel<<<NSCAN, 256, 0, stream>>>(cur, bbase);
  csr_fill_kernel<<<NE / 256, 256, 0, stream>>>(eidx, eidx + NE, cur, rowv, colv, ipos);

  prep_weights_kernel<<<1920, 256, 0, stream>>>(e1W, e2W, nW, W1T, W2T, WnT);
  prep_comp_kernel<<<195, 256, 0, stream>>>(e1W, e1b, edgeW, edgeb, WcT, b1c);
  node_embed_kernel<<<NN / 16, 256, 0, stream>>>(x, nodeW, nodeb, hf, h16);
  ea_convert_kernel<<<NE / 64, 256, 0, stream>>>(eattr, ipos, eaF);

  for (int L = 0; L < 3; ++L) {
    hipMemsetAsync(aggrF, 0, (size_t)NN * 128 * 4, stream);
    uv_kernel<<<(NN + 63) / 64, 256, 0, stream>>>(
        h16, W1T + (size_t)L * 98304, b1c + (size_t)L * 256, u16, v16);
    conv_edge_kernel<<<NE / 64, 512, 0, stream>>>(
        u16, v16, eaF, rowv, colv,
        WcT + (size_t)L * 16384,
        W2T + (size_t)L * 32768, e2b + (size_t)L * 128, aggrF);
    conv_node_kernel<<<(NN + 63) / 64, 512, 0, stream>>>(
        h16, aggrF, WnT + (size_t)L * 32768, nb + (size_t)L * 128, hf);
  }
  pool_kernel<<<NN / 16, 128, 0, stream>>>(hf, batch, gsum, gcnt);
  heads_kernel<<<NG, 128, 0, stream>>>(gsum, gcnt, sW1, sb1, sW2, sb2,
                                       hW, hb, hoW, hob, out);
}

// Round 13
// 1156.351 us; speedup vs baseline: 1.1158x; 1.1158x over previous
//
#include <hip/hip_runtime.h>

typedef _Float16 half_t;
typedef __attribute__((ext_vector_type(8))) _Float16 h8_t;
typedef __attribute__((ext_vector_type(4))) _Float16 h4_t;
typedef __attribute__((ext_vector_type(4))) float f4_t;

#define NN      50000
#define NE      800000
#define NG      256
#define NODE_IN 92
#define EDGE_IN 41

__device__ __forceinline__ float softplus_f(float x) {
  return fmaxf(x, 0.0f) + __logf(1.0f + __expf(-fabsf(x)));
}
__device__ __forceinline__ unsigned pk2(float a, float b) {
  return __builtin_bit_cast(unsigned, __builtin_amdgcn_cvt_pkrtz(a, b));
}

// ---------- weight prep: fp32 [K][N] -> f16 [N][K] (per conv layer) ----------
__global__ __launch_bounds__(256) void prep_weights_kernel(
    const float* __restrict__ e1W, const float* __restrict__ e2W,
    const float* __restrict__ nW,
    half_t* __restrict__ W1T, half_t* __restrict__ W2T, half_t* __restrict__ WnT)
{
  int idx = blockIdx.x * 256 + threadIdx.x;        // 0 .. 491519 (exact grid 1920)
  if (idx < 294912) {                              // W1T: 3 x 256 x 384
    int i = idx / 98304, rem = idx % 98304;
    int n = rem / 384, k = rem % 384;
    W1T[idx] = (half_t)e1W[i * 98304 + k * 256 + n];
  } else if (idx < 393216) {                       // W2T: 3 x 128 x 256
    int o = idx - 294912;
    int i = o / 32768, rem = o % 32768;
    int n = rem / 256, k = rem % 256;
    W2T[o] = (half_t)e2W[i * 32768 + k * 128 + n];
  } else {                                         // WnT: 3 x 128 x 256
    int o = idx - 393216;
    int i = o / 32768, rem = o % 32768;
    int n = rem / 256, k = rem % 256;
    WnT[o] = (half_t)nW[i * 32768 + k * 128 + n];
  }
}

// ---------- composite ea weights: Wc[L] = We @ W1c[L] (f16 [256][64]),
//            b1c[L] = e1b[L] + be @ W1c[L] (fp32) ----------
__global__ __launch_bounds__(256) void prep_comp_kernel(
    const float* __restrict__ e1W, const float* __restrict__ e1b,
    const float* __restrict__ eW, const float* __restrict__ eb,
    half_t* __restrict__ WcT, float* __restrict__ b1c)
{
  int idx = blockIdx.x * 256 + threadIdx.x;   // grid 195 -> 49920
  if (idx < 49152) {                          // (L, n, k): 3 x 256 x 64
    int L = idx / 16384, rem = idx % 16384;
    int n = rem / 64, k = rem % 64;
    float s = 0.f;
    if (k < EDGE_IN) {
      const float* w1 = e1W + (size_t)L * 98304 + 256 * 256 + n;  // rows 256+j
      const float* we = eW + k * 128;
      for (int j = 0; j < 128; ++j) s += we[j] * w1[(size_t)j * 256];
    }
    WcT[idx] = (half_t)s;                     // layout [L][n][k64]
  } else if (idx < 49920) {
    int o = idx - 49152;                      // (L, n): 3 x 256
    int L = o / 256, n = o % 256;
    float s = e1b[L * 256 + n];
    const float* w1 = e1W + (size_t)L * 98304 + 256 * 256 + n;
    for (int j = 0; j < 128; ++j) s += eb[j] * w1[(size_t)j * 256];
    b1c[o] = s;
  }
}

// ---------- node embedding: h = x @ node_W + node_b (fp32 + f16 copy) ----------
__global__ __launch_bounds__(256) void node_embed_kernel(
    const float* __restrict__ x, const float* __restrict__ W,
    const float* __restrict__ bias, float* __restrict__ hf,
    half_t* __restrict__ h16)
{
  __shared__ float xs[16 * NODE_IN];
  int n0 = blockIdx.x * 16;
  for (int i = threadIdx.x; i < 16 * NODE_IN; i += 256)
    xs[i] = x[(size_t)n0 * NODE_IN + i];
  __syncthreads();
  int ch = threadIdx.x & 127, g = threadIdx.x >> 7;
  float acc[8] = {0.f,0.f,0.f,0.f,0.f,0.f,0.f,0.f};
  for (int k = 0; k < NODE_IN; ++k) {
    float w = W[k * 128 + ch];
    #pragma unroll
    for (int u = 0; u < 8; ++u) acc[u] += xs[(g + 2*u) * NODE_IN + k] * w;
  }
  float bv = bias[ch];
  #pragma unroll
  for (int u = 0; u < 8; ++u) {
    int n = n0 + g + 2*u;
    float v = acc[u] + bv;
    hf[(size_t)n*128 + ch] = v;
    h16[(size_t)n*128 + ch] = (half_t)v;
  }
}

// ---------- ea convert: edge_attr fp32 -> f16 [NE][64] (K padded), CSR-permuted ----------
__global__ __launch_bounds__(256) void ea_convert_kernel(
    const float* __restrict__ ea, const int* __restrict__ ipos,
    half_t* __restrict__ eaF)
{
  __shared__ float es[64 * EDGE_IN];
  __shared__ int sip[64];
  int e0 = blockIdx.x * 64;
  for (int i = threadIdx.x; i < 64 * EDGE_IN; i += 256)
    es[i] = ea[(size_t)e0 * EDGE_IN + i];
  if (threadIdx.x < 64) sip[threadIdx.x] = ipos[e0 + threadIdx.x];
  __syncthreads();
  #pragma unroll
  for (int it = 0; it < 2; ++it) {
    int idx = threadIdx.x + it * 256;   // 0..511 = 64 edges x 8 chunks(8 cols)
    int e = idx >> 3, c = idx & 7;
    int c0 = c * 8;
    float f[8];
    #pragma unroll
    for (int j = 0; j < 8; ++j) {
      int col = c0 + j;
      f[j] = (col < EDGE_IN) ? es[e * EDGE_IN + col] : 0.f;
    }
    uint4 pk;
    pk.x = pk2(f[0], f[1]); pk.y = pk2(f[2], f[3]);
    pk.z = pk2(f[4], f[5]); pk.w = pk2(f[6], f[7]);
    *reinterpret_cast<uint4*>(eaF + (size_t)sip[e] * 64 + c0) = pk;
  }
}

// ---------- CSR build (by destination node = edge_index[1]) ----------
__global__ __launch_bounds__(256) void csr_count_kernel(
    const int* __restrict__ col, int* __restrict__ cnt)
{
  int e = blockIdx.x * 256 + threadIdx.x;
  atomicAdd(&cnt[col[e]], 1);
}

// parallel 3-kernel exclusive scan of cnt -> cur
__global__ __launch_bounds__(256) void scan_block_kernel(
    const int* __restrict__ cnt, int* __restrict__ cur, int* __restrict__ bsum)
{
  __shared__ int buf[256];
  int t = threadIdx.x;
  int i = blockIdx.x * 256 + t;
  int v = (i < NN) ? cnt[i] : 0;
  buf[t] = v;
  __syncthreads();
  for (int off = 1; off < 256; off <<= 1) {
    int y = (t >= off) ? buf[t - off] : 0;
    __syncthreads();
    buf[t] += y;
    __syncthreads();
  }
  if (i < NN) cur[i] = buf[t] - v;
  if (t == 255) bsum[blockIdx.x] = buf[255];
}

__global__ __launch_bounds__(256) void scan_top_kernel(
    const int* __restrict__ bsum, int* __restrict__ bbase, int nblk)
{
  __shared__ int buf[256];
  int t = threadIdx.x;
  int v = (t < nblk) ? bsum[t] : 0;
  buf[t] = v;
  __syncthreads();
  for (int off = 1; off < 256; off <<= 1) {
    int y = (t >= off) ? buf[t - off] : 0;
    __syncthreads();
    buf[t] += y;
    __syncthreads();
  }
  if (t < nblk) bbase[t] = buf[t] - v;
}

__global__ __launch_bounds__(256) void scan_add_kernel(
    int* __restrict__ cur, const int* __restrict__ bbase)
{
  int i = blockIdx.x * 256 + threadIdx.x;
  if (i < NN) cur[i] += bbase[blockIdx.x];
}

__global__ __launch_bounds__(256) void csr_fill_kernel(
    const int* __restrict__ row, const int* __restrict__ col,
    int* __restrict__ cur,
    int* __restrict__ rowv, int* __restrict__ colv, int* __restrict__ ipos)
{
  int e = blockIdx.x * 256 + threadIdx.x;
  int c = col[e];
  int pos = atomicAdd(&cur[c], 1);
  rowv[pos] = row[e];
  colv[pos] = c;
  ipos[e] = pos;
}

// ---------- per-layer node precompute: u = h@W1a + b1c, v = h@W1b (f16) ----------
__global__ __launch_bounds__(256) void uv_kernel(
    const half_t* __restrict__ h16, const half_t* __restrict__ W1T,
    const float* __restrict__ b1c,
    half_t* __restrict__ u16, half_t* __restrict__ v16)
{
  __shared__ char smem[64 * 256];   // 16KB: h tile [64node][128] f16, swizzled
  const int tid = threadIdx.x;
  const int n0 = blockIdx.x * 64;

  #pragma unroll
  for (int it = 0; it < 4; ++it) {
    int idx = tid + it * 256;        // 0..1023 = 64 nodes x 16 chunks(16B)
    int r = idx >> 4, c = idx & 15;
    int node = n0 + r;
    uint4 w = make_uint4(0u, 0u, 0u, 0u);
    if (node < NN) w = *reinterpret_cast<const uint4*>(h16 + (size_t)node * 128 + c * 8);
    unsigned o = (unsigned)(r * 256 + c * 16) ^ (unsigned)((r & 7) << 4);
    *reinterpret_cast<uint4*>(smem + o) = w;
  }
  __syncthreads();

  const int lane = tid & 63, wave = tid >> 6;
  const int lr = lane & 15, lg = lane >> 4;

  #pragma unroll
  for (int pass = 0; pass < 2; ++pass) {
    const half_t* Ww = W1T + (size_t)(wave * 64) * 384 + pass * 128;
    f4_t acc[4][4] = {};
    for (int ks = 0; ks < 4; ++ks) {
      h8_t a[4], b[4];
      #pragma unroll
      for (int m = 0; m < 4; ++m)
        a[m] = *reinterpret_cast<const h8_t*>(Ww + (size_t)(m * 16 + lr) * 384 + ks * 32 + lg * 8);
      #pragma unroll
      for (int n = 0; n < 4; ++n) {
        int r = n * 16 + lr;
        unsigned o = (unsigned)(r * 256 + ks * 64 + lg * 16) ^ (unsigned)((r & 7) << 4);
        b[n] = *reinterpret_cast<const h8_t*>(smem + o);
      }
      #pragma unroll
      for (int m = 0; m < 4; ++m)
        #pragma unroll
        for (int n = 0; n < 4; ++n)
          acc[m][n] = __builtin_amdgcn_mfma_f32_16x16x32_f16(a[m], b[n], acc[m][n], 0, 0, 0);
    }
    half_t* dst = pass ? v16 : u16;
    #pragma unroll
    for (int m = 0; m < 4; ++m) {
      int chb = wave * 64 + m * 16 + lg * 4;
      float bb0 = 0.f, bb1 = 0.f, bb2 = 0.f, bb3 = 0.f;
      if (pass == 0) { bb0 = b1c[chb]; bb1 = b1c[chb+1]; bb2 = b1c[chb+2]; bb3 = b1c[chb+3]; }
      #pragma unroll
      for (int n = 0; n < 4; ++n) {
        int node = n0 + n * 16 + lr;
        if (node < NN) {
          uint2 pk;
          pk.x = pk2(acc[m][n][0] + bb0, acc[m][n][1] + bb1);
          pk.y = pk2(acc[m][n][2] + bb2, acc[m][n][3] + bb3);
          *reinterpret_cast<uint2*>(dst + (size_t)node * 256 + chb) = pk;
        }
      }
    }
  }
}

// ---------- fused edge MLP + segmented scatter-reduce (CSR order, 40KB LDS):
//   GEMM1 split (acc[2][2] live, spill-free), GEMM2 single-pass (acc2[4]).
__global__ __launch_bounds__(512, 8) void conv_edge_kernel(
    const half_t* __restrict__ u16, const half_t* __restrict__ v16,
    const half_t* __restrict__ eaF,
    const int* __restrict__ rowv, const int* __restrict__ colv,
    const half_t* __restrict__ WcT,
    const half_t* __restrict__ W2T, const float* __restrict__ b2,
    float* __restrict__ aggrF)
{
  __shared__ char smem[64 * 512 + 64 * 128];  // 32KB s/P/out + 8KB ea = 40960
  const int tid = threadIdx.x;

  // bijective XCD-chunked remap
  const int nwg = gridDim.x;
  const int q = nwg >> 3, r = nwg & 7;
  const int xcd = blockIdx.x & 7, slot = blockIdx.x >> 3;
  const int swz = (xcd < r ? xcd * (q + 1) : r * (q + 1) + (xcd - r) * q) + slot;
  const int e0 = swz * 64;                    // CSR position base

  // stage s = u16[rowv] + v16[colv] -> LDS
  #pragma unroll
  for (int it = 0; it < 4; ++it) {
    int idx = tid + it * 512;        // 0..2047 = 64 edges x 32 chunks(16B)
    int e = idx >> 5, c = idx & 31;
    int nr = rowv[e0 + e], nc = colv[e0 + e];
    h8_t su = *reinterpret_cast<const h8_t*>(u16 + (size_t)nr * 256 + c * 8);
    h8_t sv = *reinterpret_cast<const h8_t*>(v16 + (size_t)nc * 256 + c * 8);
    h8_t s = su + sv;
    unsigned o = (unsigned)(e * 512 + c * 16) ^ (unsigned)((e & 7) << 4);
    *reinterpret_cast<h8_t*>(smem + o) = s;
  }
  // stage ea tile (contiguous, K=64 f16 = 128B/edge)
  {
    int e = tid >> 3, c = tid & 7;   // 512 items = 64 edges x 8 chunks(16B)
    uint4 w = *reinterpret_cast<const uint4*>(eaF + (size_t)(e0 + e) * 64 + c * 8);
    unsigned o = (unsigned)(32768 + e * 128 + c * 16) ^ (unsigned)((e & 7) << 4);
    *reinterpret_cast<uint4*>(smem + o) = w;
  }
  __syncthreads();

  const int lane = tid & 63, wave = tid >> 6;   // wave 0..7
  const int lr = lane & 15, lg = lane >> 4;

  // GEMM1 + ep1 in two edge-half passes: acc[2][2] live (16 regs)
  const half_t* W1w = WcT + (size_t)(wave * 32) * 64;
  #pragma unroll
  for (int pass = 0; pass < 2; ++pass) {
    f4_t acc[2][2] = {};
    #pragma unroll
    for (int ks = 0; ks < 2; ++ks) {
      h8_t a[2], b[2];
      #pragma unroll
      for (int m = 0; m < 2; ++m)
        a[m] = *reinterpret_cast<const h8_t*>(W1w + (size_t)(m * 16 + lr) * 64 + ks * 32 + lg * 8);
      #pragma unroll
      for (int n = 0; n < 2; ++n) {
        int e = pass * 32 + n * 16 + lr;
        unsigned o = (unsigned)(32768 + e * 128 + ks * 64 + lg * 16) ^ (unsigned)((e & 7) << 4);
        b[n] = *reinterpret_cast<const h8_t*>(smem + o);
      }
      #pragma unroll
      for (int m = 0; m < 2; ++m)
        #pragma unroll
        for (int n = 0; n < 2; ++n)
          acc[m][n] = __builtin_amdgcn_mfma_f32_16x16x32_f16(a[m], b[n], acc[m][n], 0, 0, 0);
    }
    // ep1 (this half, thread-local in-place): P = sp(acc + s)
    #pragma unroll
    for (int m = 0; m < 2; ++m) {
      int chb = wave * 32 + m * 16 + lg * 4;
      #pragma unroll
      for (int n = 0; n < 2; ++n) {
        int e = pass * 32 + n * 16 + lr;
        unsigned o = (unsigned)(e * 512 + chb * 2) ^ (unsigned)((e & 7) << 4);
        h4_t s = *reinterpret_cast<const h4_t*>(smem + o);
        float v0 = softplus_f(acc[m][n][0] + (float)s[0]);
        float v1 = softplus_f(acc[m][n][1] + (float)s[1]);
        float v2 = softplus_f(acc[m][n][2] + (float)s[2]);
        float v3 = softplus_f(acc[m][n][3] + (float)s[3]);
        uint2 pk;
        pk.x = pk2(v0, v1);
        pk.y = pk2(v2, v3);
        *reinterpret_cast<uint2*>(smem + o) = pk;
      }
    }
  }
  __syncthreads();   // P complete

  // GEMM2 single-pass: out[ch2][e] = P @ W2 (K=256); wave owns ch2 [wave*16,+16)
  const half_t* W2w = W2T + (size_t)(wave * 16) * 256;
  f4_t acc2[4] = {};
  for (int ks = 0; ks < 8; ++ks) {
    h8_t a2 = *reinterpret_cast<const h8_t*>(W2w + (size_t)lr * 256 + ks * 32 + lg * 8);
    h8_t b2v[4];
    #pragma unroll
    for (int n = 0; n < 4; ++n) {
      int e = n * 16 + lr;
      unsigned o = (unsigned)(e * 512 + ks * 64 + lg * 16) ^ (unsigned)((e & 7) << 4);
      b2v[n] = *reinterpret_cast<const h8_t*>(smem + o);
    }
    #pragma unroll
    for (int n = 0; n < 4; ++n)
      acc2[n] = __builtin_amdgcn_mfma_f32_16x16x32_f16(a2, b2v[n], acc2[n], 0, 0, 0);
  }
  __syncthreads();   // everyone done reading P before overwrite with f32 out

  // ep2: softplus -> f32 out[e][128] in LDS; scol -> ea region (free after GEMM1)
  {
    if (tid < 64)
      *reinterpret_cast<int*>(smem + 32768 + tid * 4) = colv[e0 + tid];
    int chb = wave * 16 + lg * 4;
    float bb0 = b2[chb + 0], bb1 = b2[chb + 1], bb2 = b2[chb + 2], bb3 = b2[chb + 3];
    #pragma unroll
    for (int n = 0; n < 4; ++n) {
      int e = n * 16 + lr;
      float4 v;
      v.x = softplus_f(acc2[n][0] + bb0);
      v.y = softplus_f(acc2[n][1] + bb1);
      v.z = softplus_f(acc2[n][2] + bb2);
      v.w = softplus_f(acc2[n][3] + bb3);
      unsigned o = (unsigned)(e * 512 + chb * 4) ^ (unsigned)((e & 7) << 4);
      *reinterpret_cast<float4*>(smem + o) = v;
    }
  }
  __syncthreads();

  // segmented reduce over sorted cols -> atomicAdd into aggrF
  {
    const int* scol = reinterpret_cast<const int*>(smem + 32768);
    int ch = tid & 127, g2 = tid >> 7;   // 4 groups x 16 edges
    int ebase = g2 * 16;
    float a = 0.f;
    int curc = scol[ebase];
    #pragma unroll
    for (int k = 0; k < 16; ++k) {
      int e = ebase + k;
      int c = scol[e];
      if (c != curc) {
        atomicAdd(&aggrF[(size_t)curc * 128 + ch], a);
        a = 0.f; curc = c;
      }
      unsigned o = (unsigned)(e * 512 + ch * 4) ^ (unsigned)((e & 7) << 4);
      a += *reinterpret_cast<const float*>(smem + o);
    }
    atomicAdd(&aggrF[(size_t)curc * 128 + ch], a);
  }
}

// ---------- node update: h = sp([h | aggrF] @ Wn + bn) + h  (8-wave) ----------
__global__ __launch_bounds__(512, 4) void conv_node_kernel(
    half_t* __restrict__ h16, const float* __restrict__ aggrF,
    const half_t* __restrict__ WnT, const float* __restrict__ bn,
    float* __restrict__ hf)
{
  __shared__ char smem[64 * 256 * 2];   // 32 KB A = [h | aggr] f16, swizzled
  const int tid = threadIdx.x;
  const int n0 = blockIdx.x * 64;

  #pragma unroll
  for (int it = 0; it < 4; ++it) {
    int idx = tid + it * 512;          // 0..2047 = 64 rows x 32 chunks
    int r = idx >> 5, c = idx & 31;
    int node = n0 + r;
    uint4 v = make_uint4(0u, 0u, 0u, 0u);
    if (node < NN) {
      if (c < 16) {
        v = *reinterpret_cast<const uint4*>(h16 + (size_t)node * 128 + c * 8);
      } else {
        const float* src = aggrF + (size_t)node * 128 + (c - 16) * 8;
        float4 f0 = *reinterpret_cast<const float4*>(src);
        float4 f1 = *reinterpret_cast<const float4*>(src + 4);
        v.x = pk2(f0.x, f0.y); v.y = pk2(f0.z, f0.w);
        v.z = pk2(f1.x, f1.y); v.w = pk2(f1.z, f1.w);
      }
    }
    unsigned o = (unsigned)(r * 512 + c * 16) ^ (unsigned)((r & 7) << 4);
    *reinterpret_cast<uint4*>(smem + o) = v;
  }
  __syncthreads();

  const int lane = tid & 63, wave = tid >> 6;
  const int lr = lane & 15, lg = lane >> 4;
  const int c0 = wave * 16;
  f4_t acc[4] = {};
  for (int ks = 0; ks < 8; ++ks) {
    h8_t a[4], b;
    #pragma unroll
    for (int m = 0; m < 4; ++m) {
      int row = m * 16 + lr;
      unsigned o = (unsigned)(row * 512 + ks * 64 + lg * 16) ^ (unsigned)((row & 7) << 4);
      a[m] = *reinterpret_cast<const h8_t*>(smem + o);
    }
    b = *reinterpret_cast<const h8_t*>(WnT + (size_t)(c0 + lr) * 256 + ks * 32 + lg * 8);
    #pragma unroll
    for (int m = 0; m < 4; ++m)
      acc[m] = __builtin_amdgcn_mfma_f32_16x16x32_f16(a[m], b, acc[m], 0, 0, 0);
  }
  #pragma unroll
  for (int m = 0; m < 4; ++m)
    #pragma unroll
    for (int r = 0; r < 4; ++r) {
      int row = m * 16 + lg * 4 + r;
      int col = c0 + lr;
      int node = n0 + row;
      if (node < NN) {
        float v = softplus_f(acc[m][r] + bn[col]) + hf[(size_t)node * 128 + col];
        hf[(size_t)node * 128 + col] = v;
        h16[(size_t)node * 128 + col] = (half_t)v;
      }
    }
}

// ---------- mean pool (run-length compressed atomics; batch is sorted) ----------
__global__ __launch_bounds__(128) void pool_kernel(
    const float* __restrict__ hf, const int* __restrict__ batch,
    float* __restrict__ gsum, int* __restrict__ gcnt)
{
  int t = threadIdx.x;
  int n0 = blockIdx.x * 16;
  float acc = 0.f;
  int curb = batch[n0];
  for (int i = 0; i < 16; ++i) {
    int n = n0 + i;
    int b = batch[n];
    if (b != curb) { atomicAdd(&gsum[curb * 128 + t], acc); acc = 0.f; curb = b; }
    acc += hf[(size_t)n * 128 + t];
  }
  atomicAdd(&gsum[curb * 128 + t], acc);
  if (t == 0) {
    int c = 0, cb = batch[n0];
    for (int i = 0; i < 16; ++i) {
      int b = batch[n0 + i];
      if (b != cb) { atomicAdd(&gcnt[cb], c); c = 0; cb = b; }
      ++c;
    }
    atomicAdd(&gcnt[cb], c);
  }
}

// ---------- shared MLP + task heads (one block per graph) ----------
__global__ __launch_bounds__(128) void heads_kernel(
    const float* __restrict__ gsum, const int* __restrict__ gcnt,
    const float* __restrict__ sW1, const float* __restrict__ sb1,
    const float* __restrict__ sW2, const float* __restrict__ sb2,
    const float* __restrict__ hW, const float* __restrict__ hb,
    const float* __restrict__ hoW, const float* __restrict__ hob,
    float* __restrict__ out)
{
  int b = blockIdx.x, t = threadIdx.x;
  __shared__ float va[128], vb[128], vc[128], red[128];
  float inv = 1.0f / fmaxf((float)gcnt[b], 1.0f);
  va[t] = gsum[b * 128 + t] * inv;
  __syncthreads();
  { float a = 0.f;
    for (int k = 0; k < 128; ++k) a += va[k] * sW1[k * 128 + t];
    float r = softplus_f(a + sb1[t]);
    __syncthreads(); vb[t] = r; __syncthreads(); }
  { float a = 0.f;
    for (int k = 0; k < 128; ++k) a += vb[k] * sW2[k * 128 + t];
    float r = softplus_f(a + sb2[t]);
    __syncthreads(); va[t] = r; __syncthreads(); }   // va = g2 (kept live)
  for (int p = 0; p < 3; ++p) {
    { float a = 0.f;
      for (int k = 0; k < 128; ++k) a += va[k] * hW[((p * 2 + 0) * 128 + k) * 128 + t];
      float r = softplus_f(a + hb[(p * 2 + 0) * 128 + t]);
      __syncthreads(); vb[t] = r; __syncthreads(); }
    { float a = 0.f;
      for (int k = 0; k < 128; ++k) a += vb[k] * hW[((p * 2 + 1) * 128 + k) * 128 + t];
      float r = softplus_f(a + hb[(p * 2 + 1) * 128 + t]);
      __syncthreads(); vc[t] = r; __syncthreads(); }
    red[t] = vc[t] * hoW[p * 128 + t];
    __syncthreads();
    for (int s = 64; s > 0; s >>= 1) {
      if (t < s) red[t] += red[t + s];
      __syncthreads();
    }
    if (t == 0) out[p * NG + b] = red[0] + hob[p];
    __syncthreads();
  }
}

extern "C" void kernel_launch(void* const* d_in, const int* in_sizes, int n_in,
                              void* d_out, int out_size, void* d_ws, size_t ws_size,
                              hipStream_t stream)
{
  const float* x     = (const float*)d_in[0];
  const float* eattr = (const float*)d_in[1];
  const float* nodeW = (const float*)d_in[2];
  const float* nodeb = (const float*)d_in[3];
  const float* edgeW = (const float*)d_in[4];
  const float* edgeb = (const float*)d_in[5];
  const float* e1W   = (const float*)d_in[6];
  const float* e1b   = (const float*)d_in[7];
  const float* e2W   = (const float*)d_in[8];
  const float* e2b   = (const float*)d_in[9];
  const float* nW    = (const float*)d_in[10];
  const float* nb    = (const float*)d_in[11];
  const float* sW1   = (const float*)d_in[12];
  const float* sb1   = (const float*)d_in[13];
  const float* sW2   = (const float*)d_in[14];
  const float* sb2   = (const float*)d_in[15];
  const float* hW    = (const float*)d_in[16];
  const float* hb    = (const float*)d_in[17];
  const float* hoW   = (const float*)d_in[18];
  const float* hob   = (const float*)d_in[19];
  const int*   eidx  = (const int*)d_in[20];
  const int*   batch = (const int*)d_in[21];
  float* out = (float*)d_out;

  char* base = (char*)d_ws;
  size_t woff = 0;
  auto alloc = [&](size_t bytes) -> char* {
    char* r = base + woff;
    woff = (woff + bytes + 255) & ~(size_t)255;
    return r;
  };
  float*  hf     = (float*) alloc((size_t)NN * 128 * 4);
  half_t* h16    = (half_t*)alloc((size_t)NN * 128 * 2);
  half_t* eaF    = (half_t*)alloc((size_t)NE * 64 * 2);
  float*  aggrF  = (float*) alloc((size_t)NN * 128 * 4);
  half_t* u16    = (half_t*)alloc((size_t)NN * 256 * 2);
  half_t* v16    = (half_t*)alloc((size_t)NN * 256 * 2);
  half_t* W1T    = (half_t*)alloc((size_t)3 * 256 * 384 * 2);
  half_t* W2T    = (half_t*)alloc((size_t)3 * 128 * 256 * 2);
  half_t* WnT    = (half_t*)alloc((size_t)3 * 128 * 256 * 2);
  half_t* WcT    = (half_t*)alloc((size_t)3 * 256 * 64 * 2);
  float*  b1c    = (float*) alloc((size_t)3 * 256 * 4);
  int* cnt    = (int*)alloc((size_t)NN * 4);
  int* cur    = (int*)alloc((size_t)NN * 4);
  int* bsum   = (int*)alloc(256 * 4);
  int* bbase  = (int*)alloc(256 * 4);
  int* rowv   = (int*)alloc((size_t)NE * 4);
  int* colv   = (int*)alloc((size_t)NE * 4);
  int* ipos   = (int*)alloc((size_t)NE * 4);
  float* gsum = (float*)alloc((size_t)NG * 128 * 4);
  int*   gcnt = (int*)alloc((size_t)NG * 4);
  if (woff > ws_size) return;   // workspace too small: launch nothing (fail loud)

  const int NSCAN = (NN + 255) / 256;   // 196

  hipMemsetAsync(cnt, 0, (size_t)NN * 4, stream);
  hipMemsetAsync(gsum, 0, (size_t)NG * 128 * 4, stream);
  hipMemsetAsync(gcnt, 0, (size_t)NG * 4, stream);

  csr_count_kernel<<<NE / 256, 256, 0, stream>>>(eidx + NE, cnt);
  scan_block_kernel<<<NSCAN, 256, 0, stream>>>(cnt, cur, bsum);
  scan_top_kernel<<<1, 256, 0, stream>>>(bsum, bbase, NSCAN);
  scan_add_kernel<<<NSCAN, 256, 0, stream>>>(cur, bbase);
  csr_fill_kernel<<<NE / 256, 256, 0, stream>>>(eidx, eidx + NE, cur, rowv, colv, ipos);

  prep_weights_kernel<<<1920, 256, 0, stream>>>(e1W, e2W, nW, W1T, W2T, WnT);
  prep_comp_kernel<<<195, 256, 0, stream>>>(e1W, e1b, edgeW, edgeb, WcT, b1c);
  node_embed_kernel<<<NN / 16, 256, 0, stream>>>(x, nodeW, nodeb, hf, h16);
  ea_convert_kernel<<<NE / 64, 256, 0, stream>>>(eattr, ipos, eaF);

  for (int L = 0; L < 3; ++L) {
    hipMemsetAsync(aggrF, 0, (size_t)NN * 128 * 4, stream);
    uv_kernel<<<(NN + 63) / 64, 256, 0, stream>>>(
        h16, W1T + (size_t)L * 98304, b1c + (size_t)L * 256, u16, v16);
    conv_edge_kernel<<<NE / 64, 512, 0, stream>>>(
        u16, v16, eaF, rowv, colv,
        WcT + (size_t)L * 16384,
        W2T + (size_t)L * 32768, e2b + (size_t)L * 128, aggrF);
    conv_node_kernel<<<(NN + 63) / 64, 512, 0, stream>>>(
        h16, aggrF, WnT + (size_t)L * 32768, nb + (size_t)L * 128, hf);
  }
  pool_kernel<<<NN / 16, 128, 0, stream>>>(hf, batch, gsum, gcnt);
  heads_kernel<<<NG, 128, 0, stream>>>(gsum, gcnt, sW1, sb1, sW2, sb2,
                                       hW, hb, hoW, hob, out);
}